// Round 10
// baseline (173.432 us; speedup 1.0000x reference)
//
#include <hip/hip_runtime.h>
#include <hip/hip_bf16.h>

// GAT layer, MI355X. B=32, N=512, Fin=256, F=64, H=8. fp32 in / fp32 out.
// R10 = R9 (53.6us; bitmask adj, EGFH transcendental-free P-gen, b-major
// XCD grid) restructured for 4 waves/SIMD (was 2):
//  1. W pre-packed to bf16 frag layout in d_ws by k_prep (256 KB, L2-res);
//     stage-1 B-frags are direct global 16B loads -> no WT in LDS, no
//     stage-0 staging loop (the suspected source of the constant 5.24M
//     bank conflicts). LDS 109 -> 75.3 KB -> 2 blocks/CU.
//  2. grid (32,8)->(32,8,2): per-block stage 3 covers 256 i-rows (it=2);
//     stages 0-2 duplicated per i-half (~2us device-wide, L2-absorbed).
//  3. __launch_bounds__(512,4) caps VGPR at 128 for 4 waves/SIMD.

#define ALPHA  0.2f
#define ESCALE 1.4426950408889634f   // log2(e)

typedef __bf16 bf16x8 __attribute__((ext_vector_type(8)));
typedef __bf16 bf16x4 __attribute__((ext_vector_type(4)));
typedef float  f32x4  __attribute__((ext_vector_type(4)));

#if __has_builtin(__builtin_amdgcn_exp2f)
#define EXP2(x) __builtin_amdgcn_exp2f(x)
#else
#define EXP2(x) exp2f(x)
#endif

#define HT_STRIDE 520   // 512+8: avoids 16-way conflicts on [f][j] b128 reads

struct Smem {
    __bf16 hT[64][HT_STRIDE];              // h^T [f][j]        66,560 B
    float  E[512], G[512], F[512], H[512]; //                    8,192 B
    float  asrc[64], adst[64];             //                      512 B
};                                         // 75,264 B -> 2 blocks/CU

__device__ inline bf16x8 ld8(const float* p) {
    float4 a0 = *(const float4*)p;
    float4 a1 = *(const float4*)(p + 4);
    bf16x8 r;
    r[0]=(__bf16)a0.x; r[1]=(__bf16)a0.y; r[2]=(__bf16)a0.z; r[3]=(__bf16)a0.w;
    r[4]=(__bf16)a1.x; r[5]=(__bf16)a1.y; r[6]=(__bf16)a1.z; r[7]=(__bf16)a1.w;
    return r;
}

// ---- k_pack: adj {0,1} fp32 -> bitmask. mask[(b*16+ks)*512 + i], bit j&31 --
__global__ __launch_bounds__(512) void k_pack(const float* __restrict__ adj,
                                              unsigned int* __restrict__ mask) {
    const int i = blockIdx.x, b = blockIdx.y;
    const int tid = threadIdx.x, wave = tid >> 6, lane = tid & 63;
    float v = adj[((long)b * 512 + i) * 512 + tid];          // coalesced
    unsigned long long m = __ballot(v > 0.f);                // 64 j-bits
    if (lane == 0) {
        mask[(b * 16 + 2 * wave) * 512 + i]     = (unsigned int)m;
        mask[(b * 16 + 2 * wave + 1) * 512 + i] = (unsigned int)(m >> 32);
    }
}

// ---- k_prep: W (256x512 fp32, k-major) -> WTg (512x256 bf16, c-major) -----
__global__ __launch_bounds__(512) void k_prep(const float* __restrict__ W,
                                              __bf16* __restrict__ WTg) {
    int t = blockIdx.x * 512 + threadIdx.x;   // 131072
    int c = t & 511, k = t >> 9;              // read coalesced in c
    WTg[c * 256 + k] = (__bf16)W[k * 512 + c];
}

// ---- fused GAT kernel. PRE: bitmask + packed-W path; !PRE: fallback -------
template <bool PRE>
__global__ __launch_bounds__(512, 4) void k_gat(const float* __restrict__ x,
                                                const float* __restrict__ adj,
                                                const unsigned int* __restrict__ mask,
                                                const __bf16* __restrict__ WTg,
                                                const float* __restrict__ W,
                                                const float* __restrict__ a,
                                                float* __restrict__ out) {
    __shared__ Smem sm;
    const int b = blockIdx.x, h = blockIdx.y, ihalf = blockIdx.z;
    const int tid  = threadIdx.x;
    const int wave = tid >> 6, lane = tid & 63;
    const int quad = lane >> 4, col = lane & 15;

    // stage 0: a * log2e -> LDS (consumed in stage 2; stage-1 barrier covers)
    if (tid < 128) {
        float v = a[h * 128 + tid] * ESCALE;
        if (tid < 64) sm.asrc[tid] = v; else sm.adst[tid - 64] = v;
    }

    // stage 1: h = x[b] @ W[:,h-block] -> hT[f][j] (full 512 j; MFMA)
    {
        const float* xb = x + (long)b * 512 * 256;
        const __bf16* wg = WTg + (long)h * 64 * 256;
        f32x4 acc[4][4] = {};
        for (int ks = 0; ks < 8; ++ks) {             // K = 256
            int k0 = ks * 32 + quad * 8;
            bf16x8 av[4], bv[4];
            #pragma unroll
            for (int it = 0; it < 4; ++it)           // A[m=col][k=quad*8+u]
                av[it] = ld8(xb + (long)(wave * 64 + it * 16 + col) * 256 + k0);
            #pragma unroll
            for (int nt = 0; nt < 4; ++nt) {         // B[k][n=col]
                if (PRE) {
                    bv[nt] = *(const bf16x8*)(wg + (nt * 16 + col) * 256 + k0);
                } else {
                    #pragma unroll
                    for (int u = 0; u < 8; ++u)
                        bv[nt][u] = (__bf16)W[(long)(k0 + u) * 512 + h * 64 + nt * 16 + col];
                }
            }
            #pragma unroll
            for (int it = 0; it < 4; ++it)
                #pragma unroll
                for (int nt = 0; nt < 4; ++nt)
                    acc[it][nt] = __builtin_amdgcn_mfma_f32_16x16x32_bf16(av[it], bv[nt], acc[it][nt], 0, 0, 0);
        }
        #pragma unroll
        for (int it = 0; it < 4; ++it)
            #pragma unroll
            for (int nt = 0; nt < 4; ++nt) {
                int f = nt * 16 + col;               // C/D: col=f, row=node
                int j = wave * 64 + it * 16 + quad * 4;
                bf16x4 pk = { (__bf16)acc[it][nt][0], (__bf16)acc[it][nt][1],
                              (__bf16)acc[it][nt][2], (__bf16)acc[it][nt][3] };
                *(bf16x4*)(&sm.hT[f][j]) = pk;
            }
    }
    __syncthreads();

    // stage 2: per-node score factor tables E,G,F,H (2048 exp2/block)
    {
        float as = 0.f, ad = 0.f;
        #pragma unroll 8
        for (int f = 0; f < 64; ++f) {
            float v = (float)sm.hT[f][tid];
            as += v * sm.asrc[f];
            ad += v * sm.adst[f];
        }
        sm.E[tid] = EXP2(as);            // e^{s_src}
        sm.G[tid] = EXP2(ALPHA * as);
        sm.F[tid] = EXP2(ad);
        sm.H[tid] = EXP2(ALPHA * ad);
    }
    __syncthreads();

    // stage 3: P-gen (no exp) + P@h MFMA for this block's 256 i; it=2
    {
        const int qs = quad * 8;
        float EI[2], GI[2];
        int iw[2];
        const float* arow[2];
        #pragma unroll
        for (int it = 0; it < 2; ++it) {
            int i = ihalf * 256 + wave * 32 + it * 16 + col;   // A-row m=lane&15
            iw[it] = i;
            EI[it] = sm.E[i];
            GI[it] = sm.G[i];
            if (!PRE) arow[it] = adj + ((long)b * 512 + i) * 512;
        }
        const unsigned int* mbase = mask + (long)b * 16 * 512;
        bf16x8 ones;
        #pragma unroll
        for (int u = 0; u < 8; ++u) ones[u] = (__bf16)1.0f;

        f32x4 acc[2][4] = {};
        f32x4 accs[2]   = {};                        // row sums via P@ones
        unsigned int pm[2];
        float4 pa0[2], pa1[2];
        #pragma unroll
        for (int it = 0; it < 2; ++it) {             // prefetch ks=0 (static)
            if (PRE) pm[it] = mbase[iw[it]];
            else {
                pa0[it] = *(const float4*)(arow[it] + qs);
                pa1[it] = *(const float4*)(arow[it] + qs + 4);
            }
        }
        for (int ks = 0; ks < 16; ++ks) {            // K = 512 neighbors
            int j0 = ks * 32 + qs;
            unsigned int cm[2];
            float am[2][8];
            #pragma unroll
            for (int it = 0; it < 2; ++it) {         // consume prefetch
                if (PRE) cm[it] = pm[it];
                else {
                    am[it][0]=pa0[it].x; am[it][1]=pa0[it].y;
                    am[it][2]=pa0[it].z; am[it][3]=pa0[it].w;
                    am[it][4]=pa1[it].x; am[it][5]=pa1[it].y;
                    am[it][6]=pa1[it].z; am[it][7]=pa1[it].w;
                }
            }
            if (ks < 15) {                           // refill (static regs)
                #pragma unroll
                for (int it = 0; it < 2; ++it) {
                    if (PRE) pm[it] = mbase[(ks + 1) * 512 + iw[it]];
                    else {
                        pa0[it] = *(const float4*)(arow[it] + j0 + 32);
                        pa1[it] = *(const float4*)(arow[it] + j0 + 36);
                    }
                }
            }
            f32x4 F0 = *(const f32x4*)&sm.F[j0];
            f32x4 F1 = *(const f32x4*)&sm.F[j0 + 4];
            f32x4 H0 = *(const f32x4*)&sm.H[j0];
            f32x4 H1 = *(const f32x4*)&sm.H[j0 + 4];
            float Fv[8] = {F0[0],F0[1],F0[2],F0[3],F1[0],F1[1],F1[2],F1[3]};
            float Hv[8] = {H0[0],H0[1],H0[2],H0[3],H1[0],H1[1],H1[2],H1[3]};
            bf16x8 P[2];
            #pragma unroll
            for (int it = 0; it < 2; ++it)
                #pragma unroll
                for (int u = 0; u < 8; ++u) {
                    float ef = EI[it] * Fv[u];       // e^{si+sj}
                    float gh = GI[it] * Hv[u];       // e^{0.2(si+sj)}
                    float sel = ef > 1.0f ? ef : gh; // leaky-relu in exp-space
                    float p;
                    if (PRE) p = ((cm[it] >> (qs + u)) & 1u) ? sel : 0.0f;
                    else     p = sel * am[it][u];
                    P[it][u] = (__bf16)p;
                }
            bf16x8 bv[4];
            #pragma unroll
            for (int nt = 0; nt < 4; ++nt)
                bv[nt] = *(const bf16x8*)(&sm.hT[nt * 16 + col][j0]);
            #pragma unroll
            for (int it = 0; it < 2; ++it) {
                #pragma unroll
                for (int nt = 0; nt < 4; ++nt)
                    acc[it][nt] = __builtin_amdgcn_mfma_f32_16x16x32_bf16(P[it], bv[nt], acc[it][nt], 0, 0, 0);
                accs[it] = __builtin_amdgcn_mfma_f32_16x16x32_bf16(P[it], ones, accs[it], 0, 0, 0);
            }
        }
        // epilogue: accs rows (quad*4+r) align with acc rows; no barrier
        #pragma unroll
        for (int it = 0; it < 2; ++it)
            #pragma unroll
            for (int r = 0; r < 4; ++r) {
                float s = accs[it][r];
                float inv = (s > 0.f) ? 1.0f / s : 0.f;
                int i = ihalf * 256 + wave * 32 + it * 16 + quad * 4 + r;
                float* orow = out + ((long)b * 512 + i) * 512 + h * 64;
                #pragma unroll
                for (int nt = 0; nt < 4; ++nt)
                    orow[nt * 16 + col] = acc[it][nt][r] * inv;
            }
    }
}

// ---------------- launch ---------------------------------------------------
extern "C" void kernel_launch(void* const* d_in, const int* in_sizes, int n_in,
                              void* d_out, int out_size, void* d_ws, size_t ws_size,
                              hipStream_t stream) {
    const float* x   = (const float*)d_in[0];   // (32,512,256)
    const float* adj = (const float*)d_in[1];   // (32,512,512), {0,1}
    const float* W   = (const float*)d_in[2];   // (256,512)
    const float* a   = (const float*)d_in[3];   // (8,128)
    float* out = (float*)d_out;                 // (32,512,512)

    const size_t MASK_BYTES = 32u * 16u * 512u * 4u;          // 1 MB
    const size_t WTG_BYTES  = 512u * 256u * 2u;               // 256 KB
    if (ws_size >= MASK_BYTES + WTG_BYTES) {
        unsigned int* mask = (unsigned int*)d_ws;
        __bf16* WTg = (__bf16*)((char*)d_ws + MASK_BYTES);
        k_pack<<<dim3(512, 32), 512, 0, stream>>>(adj, mask);
        k_prep<<<256, 512, 0, stream>>>(W, WTg);
        k_gat<true><<<dim3(32, 8, 2), 512, 0, stream>>>(x, adj, mask, WTg, W, a, out);
    } else {
        k_gat<false><<<dim3(32, 8, 2), 512, 0, stream>>>(x, adj, nullptr, nullptr, W, a, out);
    }
}